// Round 5
// baseline (274.880 us; speedup 1.0000x reference)
//
#include <hip/hip_runtime.h>
#include <cstdint>
#include <cstddef>

// B=2, S=512, D_MODEL=512, H=8, dk=64, N_SAMPLES=16; R = B*H*S = 8192 rows.
// JAX partitionable threefry: bits[i] = o0^o1, (o0,o1)=threefry2x32((0,42),(0,i))
// u = (float)(bits>>9) * 2^-23 ; select iff u < p ⟺ bits < (ceil(p*2^23))<<9

#define ROTL(x, r) __builtin_rotateleft32((x), (r))

#define QR8(s)                                                                \
  x0[0]+=x1[0];x0[1]+=x1[1];x0[2]+=x1[2];x0[3]+=x1[3];                        \
  x0[4]+=x1[4];x0[5]+=x1[5];x0[6]+=x1[6];x0[7]+=x1[7];                        \
  x1[0]=ROTL(x1[0],s);x1[1]=ROTL(x1[1],s);x1[2]=ROTL(x1[2],s);                \
  x1[3]=ROTL(x1[3],s);x1[4]=ROTL(x1[4],s);x1[5]=ROTL(x1[5],s);                \
  x1[6]=ROTL(x1[6],s);x1[7]=ROTL(x1[7],s);                                    \
  x1[0]^=x0[0];x1[1]^=x0[1];x1[2]^=x0[2];x1[3]^=x0[3];                        \
  x1[4]^=x0[4];x1[5]^=x0[5];x1[6]^=x0[6];x1[7]^=x0[7];
#define INJ8(X, Y)                                                            \
  x0[0]+=(X);x0[1]+=(X);x0[2]+=(X);x0[3]+=(X);                                \
  x0[4]+=(X);x0[5]+=(X);x0[6]+=(X);x0[7]+=(X);                                \
  x1[0]+=(Y);x1[1]+=(Y);x1[2]+=(Y);x1[3]+=(Y);                                \
  x1[4]+=(Y);x1[5]+=(Y);x1[6]+=(Y);x1[7]+=(Y);
#define INJ8Y(Y)                                                              \
  x1[0]+=(Y);x1[1]+=(Y);x1[2]+=(Y);x1[3]+=(Y);                                \
  x1[4]+=(Y);x1[5]+=(Y);x1[6]+=(Y);x1[7]+=(Y);

#define WAVE_FENCE() asm volatile("s_waitcnt lgkmcnt(0)" ::: "memory")

// ---------------------------------------------------------------------------
// Kernel A: QKV projection + out-init (R15 verbatim — known-good).
// grid=(32,8,4), block=256, 32x64 tiles, double-buffered LDS.
// ---------------------------------------------------------------------------
__global__ __launch_bounds__(256)
void qkv_gemm(const float* __restrict__ x,
              const float* __restrict__ Wq, const float* __restrict__ bq,
              const float* __restrict__ Wk, const float* __restrict__ bk,
              const float* __restrict__ Wv, const float* __restrict__ bv,
              const float* __restrict__ bo, float* __restrict__ outp,
              float* __restrict__ Qw, float* __restrict__ KTw,
              float* __restrict__ Vw) {
  const int tid = threadIdx.x;
  if (blockIdx.z == 3) {
    const int blk = blockIdx.y * 32 + blockIdx.x;        // 0..255
    const size_t base4 = (size_t)blk * 512 + tid;        // float4 index
    const float4* bo4 = (const float4*)bo;
    float4* out4 = (float4*)outp;
    out4[base4] = bo4[base4 & 127];
    out4[base4 + 256] = bo4[(base4 + 256) & 127];
    return;
  }
  const float* W; const float* bias;
  if (blockIdx.z == 0)      { W = Wq; bias = bq; }
  else if (blockIdx.z == 1) { W = Wk; bias = bk; }
  else                      { W = Wv; bias = bv; }

  __shared__ __align__(16) float smem[2 * (32 * 34 + 32 * 64)];
  float (*At0)[34] = (float(*)[34])smem;
  float (*Bs0)[64] = (float(*)[64])(smem + 32 * 34);
  float (*At1)[34] = (float(*)[34])(smem + 3136);
  float (*Bs1)[64] = (float(*)[64])(smem + 3136 + 32 * 34);
  float (*T2)[34]  = (float(*)[34])smem;                 // 64x34 (K epilogue)

  const int tx = tid & 15, ty = tid >> 4;
  const int row0 = blockIdx.x * 32, col0 = blockIdx.y * 64;
  float acc[2][4] = {};

  const int ar = tid >> 3;
  const int kc = (tid & 7) << 2;
  const int br0 = tid >> 4,         bc0 = (tid & 15) << 2;
  const int br1 = (tid + 256) >> 4, bc1 = ((tid + 256) & 15) << 2;

  float4 aR, bR0, bR1;
  aR  = *(const float4*)&x[(size_t)(row0 + ar) * 512 + kc];
  bR0 = *(const float4*)&W[(size_t)br0 * 512 + col0 + bc0];
  bR1 = *(const float4*)&W[(size_t)br1 * 512 + col0 + bc1];

  At0[kc + 0][ar] = aR.x; At0[kc + 1][ar] = aR.y;
  At0[kc + 2][ar] = aR.z; At0[kc + 3][ar] = aR.w;
  *(float4*)&Bs0[br0][bc0] = bR0;
  *(float4*)&Bs0[br1][bc1] = bR1;
  __syncthreads();

  float (*Atc)[34] = At0; float (*Bsc)[64] = Bs0;
  float (*Atn)[34] = At1; float (*Bsn)[64] = Bs1;

  for (int kk = 0; kk < 512; kk += 32) {
    if (kk < 480) {
      const int kn = kk + 32;
      aR  = *(const float4*)&x[(size_t)(row0 + ar) * 512 + kn + kc];
      bR0 = *(const float4*)&W[(size_t)(kn + br0) * 512 + col0 + bc0];
      bR1 = *(const float4*)&W[(size_t)(kn + br1) * 512 + col0 + bc1];
    }
#pragma unroll
    for (int p = 0; p < 32; ++p) {
      const float2 a2 = *(const float2*)&Atc[p][ty << 1];
      const float4 b4 = *(const float4*)&Bsc[p][tx << 2];
      acc[0][0] = fmaf(a2.x, b4.x, acc[0][0]); acc[0][1] = fmaf(a2.x, b4.y, acc[0][1]);
      acc[0][2] = fmaf(a2.x, b4.z, acc[0][2]); acc[0][3] = fmaf(a2.x, b4.w, acc[0][3]);
      acc[1][0] = fmaf(a2.y, b4.x, acc[1][0]); acc[1][1] = fmaf(a2.y, b4.y, acc[1][1]);
      acc[1][2] = fmaf(a2.y, b4.z, acc[1][2]); acc[1][3] = fmaf(a2.y, b4.w, acc[1][3]);
    }
    if (kk < 480) {
      Atn[kc + 0][ar] = aR.x; Atn[kc + 1][ar] = aR.y;
      Atn[kc + 2][ar] = aR.z; Atn[kc + 3][ar] = aR.w;
      *(float4*)&Bsn[br0][bc0] = bR0;
      *(float4*)&Bsn[br1][bc1] = bR1;
    }
    __syncthreads();
    float (*tA)[34] = Atc; Atc = Atn; Atn = tA;
    float (*tB)[64] = Bsc; Bsc = Bsn; Bsn = tB;
  }

  const int h = blockIdx.y;
  if (blockIdx.z == 0 || blockIdx.z == 2) {
    float* dst = (blockIdx.z == 0) ? Qw : Vw;
#pragma unroll
    for (int i = 0; i < 2; ++i) {
      const int row = row0 + (ty << 1) + i;
      const int b = row >> 9, s = row & 511;
#pragma unroll
      for (int j = 0; j < 4; ++j) {
        const int col = col0 + (tx << 2) + j;
        const int d = col & 63;
        dst[(((size_t)(b * 8 + h) * 512 + s) * 64) + d] = acc[i][j] + bias[col];
      }
    }
  } else {
#pragma unroll
    for (int i = 0; i < 2; ++i) {
#pragma unroll
      for (int j = 0; j < 4; ++j) {
        const int col = col0 + (tx << 2) + j;
        T2[(tx << 2) + j][(ty << 1) + i] = acc[i][j] + bias[col];
      }
    }
    __syncthreads();
    const int b = row0 >> 9;
    const int s0 = row0 & 511;
#pragma unroll
    for (int i2 = 0; i2 < 2; ++i2) {
      const int idx = tid + (i2 << 8);
      const int c = idx >> 3, seg = idx & 7;
      float* dst = KTw + (((size_t)(b * 8 + h) * 64 + c) << 9) + s0 + (seg << 2);
      *(float4*)dst = *(const float4*)&T2[c][seg << 2];
    }
  }
}

// ---------------------------------------------------------------------------
// Kernel B (R16 HYBRID): R13 score phase + R13 out-proj (block-shared loads)
// + R14's PROVEN per-wave row pipeline in the middle (softmax, thresholds,
// threefry, weights, wa, ballot-walk sparse V) -> 3 block barriers (was ~28).
// Wave w owns row rbase+w. tf aliases scs[w] (scores dead after owner-lane
// read); wa aliases the threshold buffer (dead after RNG). Threefry counter
// set per row unchanged (lane l: sample n=l>>2, chunk gl=l&3) -> identical
// draw bits; threshold fp re-association = same class R14 already passed.
// LDS 18.4 KB -> 8 blocks/CU.
// ---------------------------------------------------------------------------
__global__ __launch_bounds__(256)
void fused_sample(const float* __restrict__ Q, const float* __restrict__ KT,
                  const float* __restrict__ V, const float* __restrict__ Wo,
                  float* __restrict__ outp) {
  const int bx = blockIdx.x;
  // XCD swizzle: each XCD gets 256 consecutive blocks = 1024 consecutive rows.
  const int rbase = ((((bx & 7) << 8) | (bx >> 3)) << 2);   // 0..8188 step 4
  const int bh = rbase >> 9, q0 = rbase & 511;
  const int b = rbase >> 12, h = (rbase >> 9) & 7;
  const int tid = threadIdx.x;
  const int w = tid >> 6, l = tid & 63;

  __shared__ __align__(16) float    qs[4][64];
  __shared__ __align__(16) float    scs[4][512];   // scores -> tf (per-wave)
  __shared__ __align__(16) uint32_t pscu[4][512];  // thresholds -> wa
  __shared__ __align__(16) float    o_sT[64][4];   // [d][row]

  qs[w][l] = Q[((size_t)bh * 512 + q0 + w) * 64 + l];
  __syncthreads();

  // ---- scores for all 4 rows (R13 verbatim: bit-exact fmaf order) ----
  {
    const float* Kp = KT + (size_t)bh * 64 * 512 + tid;   // [d][k], stride 512
    float s00 = 0.f, s01 = 0.f, s10 = 0.f, s11 = 0.f;
    float s20 = 0.f, s21 = 0.f, s30 = 0.f, s31 = 0.f;
#pragma unroll
    for (int d4 = 0; d4 < 16; ++d4) {
      float k0v[4], k1v[4];
#pragma unroll
      for (int j = 0; j < 4; ++j) {
        k0v[j] = Kp[(size_t)(d4 * 4 + j) * 512];
        k1v[j] = Kp[(size_t)(d4 * 4 + j) * 512 + 256];
      }
      const float4 q0v = *(const float4*)&qs[0][d4 << 2];
      const float4 q1v = *(const float4*)&qs[1][d4 << 2];
      const float4 q2v = *(const float4*)&qs[2][d4 << 2];
      const float4 q3v = *(const float4*)&qs[3][d4 << 2];
      s00 = fmaf(q0v.x, k0v[0], s00); s00 = fmaf(q0v.y, k0v[1], s00);
      s00 = fmaf(q0v.z, k0v[2], s00); s00 = fmaf(q0v.w, k0v[3], s00);
      s01 = fmaf(q0v.x, k1v[0], s01); s01 = fmaf(q0v.y, k1v[1], s01);
      s01 = fmaf(q0v.z, k1v[2], s01); s01 = fmaf(q0v.w, k1v[3], s01);
      s10 = fmaf(q1v.x, k0v[0], s10); s10 = fmaf(q1v.y, k0v[1], s10);
      s10 = fmaf(q1v.z, k0v[2], s10); s10 = fmaf(q1v.w, k0v[3], s10);
      s11 = fmaf(q1v.x, k1v[0], s11); s11 = fmaf(q1v.y, k1v[1], s11);
      s11 = fmaf(q1v.z, k1v[2], s11); s11 = fmaf(q1v.w, k1v[3], s11);
      s20 = fmaf(q2v.x, k0v[0], s20); s20 = fmaf(q2v.y, k0v[1], s20);
      s20 = fmaf(q2v.z, k0v[2], s20); s20 = fmaf(q2v.w, k0v[3], s20);
      s21 = fmaf(q2v.x, k1v[0], s21); s21 = fmaf(q2v.y, k1v[1], s21);
      s21 = fmaf(q2v.z, k1v[2], s21); s21 = fmaf(q2v.w, k1v[3], s21);
      s30 = fmaf(q3v.x, k0v[0], s30); s30 = fmaf(q3v.y, k0v[1], s30);
      s30 = fmaf(q3v.z, k0v[2], s30); s30 = fmaf(q3v.w, k0v[3], s30);
      s31 = fmaf(q3v.x, k1v[0], s31); s31 = fmaf(q3v.y, k1v[1], s31);
      s31 = fmaf(q3v.z, k1v[2], s31); s31 = fmaf(q3v.w, k1v[3], s31);
    }
    scs[0][tid] = s00 * 0.125f; scs[0][tid + 256] = s01 * 0.125f;
    scs[1][tid] = s10 * 0.125f; scs[1][tid + 256] = s11 * 0.125f;
    scs[2][tid] = s20 * 0.125f; scs[2][tid + 256] = s21 * 0.125f;
    scs[3][tid] = s30 * 0.125f; scs[3][tid + 256] = s31 * 0.125f;
  }
  __syncthreads();

  // ================== per-wave row pipeline (row = rbase + w) ==============
  const int r = rbase + w;
  float* tf = scs[w];                           // scores now wave-local
  uint32_t* thr = pscu[w];
  uint4* thr4 = (uint4*)thr;
  float* wa = (float*)thr;                      // alias (post-RNG)

  // ---- softmax: lane l covers k = 4l..4l+3 and 256+4l..4l+3 ----
  const float4 sa = *(const float4*)&tf[l << 2];
  const float4 sb = *(const float4*)&tf[256 + (l << 2)];
  float mx = fmaxf(fmaxf(fmaxf(sa.x, sa.y), fmaxf(sa.z, sa.w)),
                   fmaxf(fmaxf(sb.x, sb.y), fmaxf(sb.z, sb.w)));
#pragma unroll
  for (int m = 1; m < 64; m <<= 1) mx = fmaxf(mx, __shfl_xor(mx, m));
  const float e0 = expf(sa.x - mx), e1 = expf(sa.y - mx);
  const float e2 = expf(sa.z - mx), e3 = expf(sa.w - mx);
  const float e4 = expf(sb.x - mx), e5 = expf(sb.y - mx);
  const float e6 = expf(sb.z - mx), e7 = expf(sb.w - mx);
  float tot = ((e0 + e1) + (e2 + e3)) + ((e4 + e5) + (e6 + e7));
#pragma unroll
  for (int m = 1; m < 64; m <<= 1) tot += __shfl_xor(tot, m);
  const float t0 = e0 / tot, t1 = e1 / tot, t2 = e2 / tot, t3 = e3 / tot;
  const float t4 = e4 / tot, t5 = e5 / tot, t6 = e6 / tot, t7 = e7 / tot;
  const float p0 = fmaf(0.5f, t0, 0.0009765625f);
  const float p1 = fmaf(0.5f, t1, 0.0009765625f);
  const float p2 = fmaf(0.5f, t2, 0.0009765625f);
  const float p3 = fmaf(0.5f, t3, 0.0009765625f);
  const float p4 = fmaf(0.5f, t4, 0.0009765625f);
  const float p5 = fmaf(0.5f, t5, 0.0009765625f);
  const float p6 = fmaf(0.5f, t6, 0.0009765625f);
  const float p7 = fmaf(0.5f, t7, 0.0009765625f);
  {
    // tf overwrite: own-lane slots only (read above, write-after-read safe)
    *(float4*)&tf[l << 2]         = make_float4(t0, t1, t2, t3);
    *(float4*)&tf[256 + (l << 2)] = make_float4(t4, t5, t6, t7);
    // thresholds, R14-verified swizzle (uint4 reads in RNG loop)
    uint4 ta, tb;
    ta.x = ((uint32_t)ceilf(p0 * 8388608.0f)) << 9;
    ta.y = ((uint32_t)ceilf(p1 * 8388608.0f)) << 9;
    ta.z = ((uint32_t)ceilf(p2 * 8388608.0f)) << 9;
    ta.w = ((uint32_t)ceilf(p3 * 8388608.0f)) << 9;
    tb.x = ((uint32_t)ceilf(p4 * 8388608.0f)) << 9;
    tb.y = ((uint32_t)ceilf(p5 * 8388608.0f)) << 9;
    tb.z = ((uint32_t)ceilf(p6 * 8388608.0f)) << 9;
    tb.w = ((uint32_t)ceilf(p7 * 8388608.0f)) << 9;
    thr4[((l & 31) << 2) + (l >> 5)]     = ta;   // k = 4l..4l+3
    thr4[((l & 31) << 2) + (l >> 5) + 2] = tb;   // k = 256+4l..+3
  }
  float ql = (((1.f - p0) * (1.f - p1)) * ((1.f - p2) * (1.f - p3))) *
             (((1.f - p4) * (1.f - p5)) * ((1.f - p6) * (1.f - p7)));
#pragma unroll
  for (int m = 1; m < 64; m <<= 1) ql *= __shfl_xor(ql, m);
  const float Qrow = ql;
  WAVE_FENCE();   // tf/thr visible wave-wide

  // ---- sampling: lane l = sample n=l>>2, k-chunk [gl*128, +128) ----
  const int n = l >> 2, gl = l & 3;
  const uint32_t cbase =
      (uint32_t)r * 8192u + (uint32_t)n * 512u + (uint32_t)(gl << 7) + 42u;
  unsigned long long lo = 0ull, hi = 0ull;
  for (int u = 0; u < 16; ++u) {                 // 16 blocks of 8 draws
    uint32_t x0[8], x1[8];
    const uint32_t cb = cbase + (uint32_t)(u << 3);
#pragma unroll
    for (int i = 0; i < 8; ++i) {
      const uint32_t c = cb + (uint32_t)i;
      x0[i] = c;                        // round-1 fold: x0 was 0
      x1[i] = ROTL(c, 13) ^ c;
    }
    QR8(15) QR8(26) QR8(6)
    INJ8(42u, 0x1BD11BF1u)
    QR8(17) QR8(29) QR8(16) QR8(24)
    INJ8(0x1BD11BF0u, 2u)
    QR8(13) QR8(15) QR8(26) QR8(6)
    INJ8Y(45u)
    QR8(17) QR8(29) QR8(16) QR8(24)
    INJ8(42u, 0x1BD11BF4u)
    QR8(13) QR8(15) QR8(26) QR8(6)
    INJ8(0x1BD11BF0u, 5u)
    const uint4 pA = thr4[(u << 3) + gl];
    const uint4 pB = thr4[(u << 3) + 4 + gl];
    uint32_t byte = 0u;
    byte |= (uint32_t)((x0[0] ^ x1[0]) < pA.x) << 0;
    byte |= (uint32_t)((x0[1] ^ x1[1]) < pA.y) << 1;
    byte |= (uint32_t)((x0[2] ^ x1[2]) < pA.z) << 2;
    byte |= (uint32_t)((x0[3] ^ x1[3]) < pA.w) << 3;
    byte |= (uint32_t)((x0[4] ^ x1[4]) < pB.x) << 4;
    byte |= (uint32_t)((x0[5] ^ x1[5]) < pB.y) << 5;
    byte |= (uint32_t)((x0[6] ^ x1[6]) < pB.z) << 6;
    byte |= (uint32_t)((x0[7] ^ x1[7]) < pB.w) << 7;
    const int sh = (u & 7) << 3;
    if (u < 8) lo |= (unsigned long long)byte << sh;
    else       hi |= (unsigned long long)byte << sh;
  }

  // rare path: selected-term products (expected ~0.25 bits per lane)
  float ptl = 1.f, ratl = 1.f;
  int cl = __popcll(lo) + __popcll(hi);
  {
    unsigned long long bb = lo;
    while (bb) {
      const int j = __builtin_ctzll(bb);
      bb &= bb - 1ull;
      const float tv = tf[(gl << 7) + j];
      const float p = fmaf(0.5f, tv, 0.0009765625f);
      ptl *= tv;
      ratl *= p / (1.f - p);
    }
    bb = hi;
    while (bb) {
      const int j = __builtin_ctzll(bb);
      bb &= bb - 1ull;
      const float tv = tf[(gl << 7) + 64 + j];
      const float p = fmaf(0.5f, tv, 0.0009765625f);
      ptl *= tv;
      ratl *= p / (1.f - p);
    }
  }
#pragma unroll
  for (int m = 1; m < 4; m <<= 1) {
    ptl *= __shfl_xor(ptl, m);
    ratl *= __shfl_xor(ratl, m);
    cl += __shfl_xor(cl, m);
  }
  const float pp = Qrow * ratl;
  const float wl = (cl > 0 && pp > 0.f) ? (ptl / fmaxf(pp, 1e-38f)) : 0.f;
  float wsum = (gl == 0) ? wl : 0.f;
#pragma unroll
  for (int m = 1; m < 64; m <<= 1) wsum += __shfl_xor(wsum, m);
  const float wn = (wsum > 0.f) ? (wl / fmaxf(wsum, 1e-38f)) : 0.0625f;

  // ---- accumulate wa (aliases thr; all thr reads done) ----
  WAVE_FENCE();
  *(float4*)&wa[l << 2]         = make_float4(0.f, 0.f, 0.f, 0.f);
  *(float4*)&wa[256 + (l << 2)] = make_float4(0.f, 0.f, 0.f, 0.f);
  WAVE_FENCE();
  {
    unsigned long long bb = lo;
    while (bb) {
      const int j = __builtin_ctzll(bb);
      bb &= bb - 1ull;
      atomicAdd(&wa[(gl << 7) + j], wn);
    }
    bb = hi;
    while (bb) {
      const int j = __builtin_ctzll(bb);
      bb &= bb - 1ull;
      atomicAdd(&wa[(gl << 7) + 64 + j], wn);
    }
  }
  WAVE_FENCE();

  // ---- row weight sum + sparse attn @ V (lane l owns d=l) ----
  float sp = 0.f;
#pragma unroll
  for (int c = 0; c < 8; ++c) sp += wa[(c << 6) + l];
#pragma unroll
  for (int m = 1; m < 64; m <<= 1) sp += __shfl_xor(sp, m);
  const float was = sp;

  const float* Vb = V + ((size_t)(b * 8 + h) * 512) * 64;
  float o = 0.f;
  if (was > 0.f) {
    const float inv = 1.f / fmaxf(was, 1e-38f);
#pragma unroll 1
    for (int c = 0; c < 8; ++c) {
      const float v = wa[(c << 6) + l];
      unsigned long long mask = __ballot(v > 0.f);
      while (mask) {
        const int j = __builtin_ctzll(mask);
        mask &= mask - 1ull;
        const int k = (c << 6) + j;
        const float wv = wa[k];                 // broadcast read
        o = fmaf(wv * inv, Vb[(size_t)k * 64 + l], o);
      }
    }
  } else {
    for (int k = 0; k < 512; ++k) o += Vb[(size_t)k * 64 + l];
    o *= 0.001953125f;
  }
  o_sT[l][w] = o;
  __syncthreads();

  // ---- out-projection (R13 form): Wo loads shared across the 4 rows ----
  {
    const float* Wh = Wo + ((size_t)h * 64) * 512;
    float a00 = 0.f, a01 = 0.f, a10 = 0.f, a11 = 0.f;
    float a20 = 0.f, a21 = 0.f, a30 = 0.f, a31 = 0.f;
#pragma unroll 8
    for (int dd = 0; dd < 64; ++dd) {
      const float4 o4 = *(const float4*)&o_sT[dd][0];   // broadcast b128
      const float w0 = Wh[(size_t)dd * 512 + tid];
      const float w1 = Wh[(size_t)dd * 512 + tid + 256];
      a00 = fmaf(o4.x, w0, a00); a01 = fmaf(o4.x, w1, a01);
      a10 = fmaf(o4.y, w0, a10); a11 = fmaf(o4.y, w1, a11);
      a20 = fmaf(o4.z, w0, a20); a21 = fmaf(o4.z, w1, a21);
      a30 = fmaf(o4.w, w0, a30); a31 = fmaf(o4.w, w1, a31);
    }
    float* orow = outp + ((size_t)(b * 512 + q0)) * 512;
    atomicAdd(&orow[tid], a00);         atomicAdd(&orow[tid + 256], a01);
    atomicAdd(&orow[512 + tid], a10);   atomicAdd(&orow[512 + tid + 256], a11);
    atomicAdd(&orow[1024 + tid], a20);  atomicAdd(&orow[1024 + tid + 256], a21);
    atomicAdd(&orow[1536 + tid], a30);  atomicAdd(&orow[1536 + tid + 256], a31);
  }
}

// ---------------------------------------------------------------------------
extern "C" void kernel_launch(void* const* d_in, const int* in_sizes, int n_in,
                              void* d_out, int out_size, void* d_ws,
                              size_t ws_size, hipStream_t stream) {
  const float* x  = (const float*)d_in[0];
  const float* Wq = (const float*)d_in[1];
  const float* bq = (const float*)d_in[2];
  const float* Wk = (const float*)d_in[3];
  const float* bk = (const float*)d_in[4];
  const float* Wv = (const float*)d_in[5];
  const float* bv = (const float*)d_in[6];
  const float* Wo = (const float*)d_in[7];
  const float* bo = (const float*)d_in[8];
  float* out = (float*)d_out;

  float* ws = (float*)d_ws;
  float* Qw = ws;                  // 524288 f32  [B,H,S,dk]
  float* KT = ws + 524288;         // 524288     [B,H,dk,S]
  float* Vw = ws + 1048576;        // 524288     [B,H,S,dk]

  dim3 gq(32, 8, 4);
  qkv_gemm<<<gq, 256, 0, stream>>>(x, Wq, bq, Wk, bk, Wv, bv, bo, out,
                                   Qw, KT, Vw);
  fused_sample<<<2048, 256, 0, stream>>>(Qw, KT, Vw, Wo, out);
}

// Round 6
// 251.386 us; speedup vs baseline: 1.0935x; 1.0935x over previous
//
#include <hip/hip_runtime.h>
#include <cstdint>
#include <cstddef>

// B=2, S=512, D_MODEL=512, H=8, dk=64, N_SAMPLES=16; R = B*H*S = 8192 rows.
// JAX partitionable threefry: bits[i] = o0^o1, (o0,o1)=threefry2x32((0,42),(0,i))
// u = (float)(bits>>9) * 2^-23 ; select iff u < p ⟺ bits < (ceil(p*2^23))<<9

#define ROTL(x, r) __builtin_rotateleft32((x), (r))

#define QR8(s)                                                                \
  x0[0]+=x1[0];x0[1]+=x1[1];x0[2]+=x1[2];x0[3]+=x1[3];                        \
  x0[4]+=x1[4];x0[5]+=x1[5];x0[6]+=x1[6];x0[7]+=x1[7];                        \
  x1[0]=ROTL(x1[0],s);x1[1]=ROTL(x1[1],s);x1[2]=ROTL(x1[2],s);                \
  x1[3]=ROTL(x1[3],s);x1[4]=ROTL(x1[4],s);x1[5]=ROTL(x1[5],s);                \
  x1[6]=ROTL(x1[6],s);x1[7]=ROTL(x1[7],s);                                    \
  x1[0]^=x0[0];x1[1]^=x0[1];x1[2]^=x0[2];x1[3]^=x0[3];                        \
  x1[4]^=x0[4];x1[5]^=x0[5];x1[6]^=x0[6];x1[7]^=x0[7];
#define INJ8(X, Y)                                                            \
  x0[0]+=(X);x0[1]+=(X);x0[2]+=(X);x0[3]+=(X);                                \
  x0[4]+=(X);x0[5]+=(X);x0[6]+=(X);x0[7]+=(X);                                \
  x1[0]+=(Y);x1[1]+=(Y);x1[2]+=(Y);x1[3]+=(Y);                                \
  x1[4]+=(Y);x1[5]+=(Y);x1[6]+=(Y);x1[7]+=(Y);
#define INJ8Y(Y)                                                              \
  x1[0]+=(Y);x1[1]+=(Y);x1[2]+=(Y);x1[3]+=(Y);                                \
  x1[4]+=(Y);x1[5]+=(Y);x1[6]+=(Y);x1[7]+=(Y);

// ---------------------------------------------------------------------------
// Kernel A: QKV projection + out-init (R15 verbatim — known-good).
// grid=(32,8,4), block=256, 32x64 tiles, double-buffered LDS.
// ---------------------------------------------------------------------------
__global__ __launch_bounds__(256)
void qkv_gemm(const float* __restrict__ x,
              const float* __restrict__ Wq, const float* __restrict__ bq,
              const float* __restrict__ Wk, const float* __restrict__ bk,
              const float* __restrict__ Wv, const float* __restrict__ bv,
              const float* __restrict__ bo, float* __restrict__ outp,
              float* __restrict__ Qw, float* __restrict__ KTw,
              float* __restrict__ Vw) {
  const int tid = threadIdx.x;
  if (blockIdx.z == 3) {
    const int blk = blockIdx.y * 32 + blockIdx.x;        // 0..255
    const size_t base4 = (size_t)blk * 512 + tid;        // float4 index
    const float4* bo4 = (const float4*)bo;
    float4* out4 = (float4*)outp;
    out4[base4] = bo4[base4 & 127];
    out4[base4 + 256] = bo4[(base4 + 256) & 127];
    return;
  }
  const float* W; const float* bias;
  if (blockIdx.z == 0)      { W = Wq; bias = bq; }
  else if (blockIdx.z == 1) { W = Wk; bias = bk; }
  else                      { W = Wv; bias = bv; }

  __shared__ __align__(16) float smem[2 * (32 * 34 + 32 * 64)];
  float (*At0)[34] = (float(*)[34])smem;
  float (*Bs0)[64] = (float(*)[64])(smem + 32 * 34);
  float (*At1)[34] = (float(*)[34])(smem + 3136);
  float (*Bs1)[64] = (float(*)[64])(smem + 3136 + 32 * 34);
  float (*T2)[34]  = (float(*)[34])smem;                 // 64x34 (K epilogue)

  const int tx = tid & 15, ty = tid >> 4;
  const int row0 = blockIdx.x * 32, col0 = blockIdx.y * 64;
  float acc[2][4] = {};

  const int ar = tid >> 3;
  const int kc = (tid & 7) << 2;
  const int br0 = tid >> 4,         bc0 = (tid & 15) << 2;
  const int br1 = (tid + 256) >> 4, bc1 = ((tid + 256) & 15) << 2;

  float4 aR, bR0, bR1;
  aR  = *(const float4*)&x[(size_t)(row0 + ar) * 512 + kc];
  bR0 = *(const float4*)&W[(size_t)br0 * 512 + col0 + bc0];
  bR1 = *(const float4*)&W[(size_t)br1 * 512 + col0 + bc1];

  At0[kc + 0][ar] = aR.x; At0[kc + 1][ar] = aR.y;
  At0[kc + 2][ar] = aR.z; At0[kc + 3][ar] = aR.w;
  *(float4*)&Bs0[br0][bc0] = bR0;
  *(float4*)&Bs0[br1][bc1] = bR1;
  __syncthreads();

  float (*Atc)[34] = At0; float (*Bsc)[64] = Bs0;
  float (*Atn)[34] = At1; float (*Bsn)[64] = Bs1;

  for (int kk = 0; kk < 512; kk += 32) {
    if (kk < 480) {
      const int kn = kk + 32;
      aR  = *(const float4*)&x[(size_t)(row0 + ar) * 512 + kn + kc];
      bR0 = *(const float4*)&W[(size_t)(kn + br0) * 512 + col0 + bc0];
      bR1 = *(const float4*)&W[(size_t)(kn + br1) * 512 + col0 + bc1];
    }
#pragma unroll
    for (int p = 0; p < 32; ++p) {
      const float2 a2 = *(const float2*)&Atc[p][ty << 1];
      const float4 b4 = *(const float4*)&Bsc[p][tx << 2];
      acc[0][0] = fmaf(a2.x, b4.x, acc[0][0]); acc[0][1] = fmaf(a2.x, b4.y, acc[0][1]);
      acc[0][2] = fmaf(a2.x, b4.z, acc[0][2]); acc[0][3] = fmaf(a2.x, b4.w, acc[0][3]);
      acc[1][0] = fmaf(a2.y, b4.x, acc[1][0]); acc[1][1] = fmaf(a2.y, b4.y, acc[1][1]);
      acc[1][2] = fmaf(a2.y, b4.z, acc[1][2]); acc[1][3] = fmaf(a2.y, b4.w, acc[1][3]);
    }
    if (kk < 480) {
      Atn[kc + 0][ar] = aR.x; Atn[kc + 1][ar] = aR.y;
      Atn[kc + 2][ar] = aR.z; Atn[kc + 3][ar] = aR.w;
      *(float4*)&Bsn[br0][bc0] = bR0;
      *(float4*)&Bsn[br1][bc1] = bR1;
    }
    __syncthreads();
    float (*tA)[34] = Atc; Atc = Atn; Atn = tA;
    float (*tB)[64] = Bsc; Bsc = Bsn; Bsn = tB;
  }

  const int h = blockIdx.y;
  if (blockIdx.z == 0 || blockIdx.z == 2) {
    float* dst = (blockIdx.z == 0) ? Qw : Vw;
#pragma unroll
    for (int i = 0; i < 2; ++i) {
      const int row = row0 + (ty << 1) + i;
      const int b = row >> 9, s = row & 511;
#pragma unroll
      for (int j = 0; j < 4; ++j) {
        const int col = col0 + (tx << 2) + j;
        const int d = col & 63;
        dst[(((size_t)(b * 8 + h) * 512 + s) * 64) + d] = acc[i][j] + bias[col];
      }
    }
  } else {
#pragma unroll
    for (int i = 0; i < 2; ++i) {
#pragma unroll
      for (int j = 0; j < 4; ++j) {
        const int col = col0 + (tx << 2) + j;
        T2[(tx << 2) + j][(ty << 1) + i] = acc[i][j] + bias[col];
      }
    }
    __syncthreads();
    const int b = row0 >> 9;
    const int s0 = row0 & 511;
#pragma unroll
    for (int i2 = 0; i2 < 2; ++i2) {
      const int idx = tid + (i2 << 8);
      const int c = idx >> 3, seg = idx & 7;
      float* dst = KTw + (((size_t)(b * 8 + h) * 64 + c) << 9) + s0 + (seg << 2);
      *(float4*)dst = *(const float4*)&T2[c][seg << 2];
    }
  }
}

// ---------------------------------------------------------------------------
// Kernel B (R17): R13's exact thread->work mappings, but reduction phases
// BATCHED across the 4 rows: one barrier serves all 4 rows' cross-wave
// reductions (29 barriers -> 9), and the 4 independent shfl chains overlap.
// RNG bit-identical to R13 (same n=tid>>4/t=tid&15 mapping, same counters,
// same unrolled 8-draw groups, same swizzled threshold reads from pscu[rr]).
// bits saved to bitsS for the wa-atomic phase; wa aliases pscu (dead after
// RNG); V phase per-wave (wave w owns row w, ballot walk — no list/cnt).
// LDS ~23 KB -> 6 blocks/CU.
// ---------------------------------------------------------------------------
__global__ __launch_bounds__(256)
void fused_sample(const float* __restrict__ Q, const float* __restrict__ KT,
                  const float* __restrict__ V, const float* __restrict__ Wo,
                  float* __restrict__ outp) {
  const int bx = blockIdx.x;
  // XCD swizzle: each XCD gets 256 consecutive blocks = 1024 consecutive rows.
  const int rbase = ((((bx & 7) << 8) | (bx >> 3)) << 2);   // 0..8188 step 4
  const int bh = rbase >> 9, q0 = rbase & 511;
  const int b = rbase >> 12, h = (rbase >> 9) & 7;
  const int tid = threadIdx.x;
  const int w = tid >> 6, l = tid & 63;

  __shared__ __align__(16) float    qs[4][64];
  __shared__ __align__(16) float    tfs[4][512];   // scores -> tf
  __shared__ __align__(16) uint32_t pscu[4][512];  // thresholds -> wa (alias)
  __shared__ __align__(16) uint32_t bitsS[4][256];
  __shared__ float redA[4][4], redB[4][4], redQ[4][4], redS[4][4];
  __shared__ float wr[4][16];
  __shared__ __align__(16) float o_sT[64][4];

  qs[w][l] = Q[((size_t)bh * 512 + q0 + w) * 64 + l];
  __syncthreads();

  // ---- scores for all 4 rows (R13 verbatim: bit-exact fmaf order) ----
  {
    const float* Kp = KT + (size_t)bh * 64 * 512 + tid;   // [d][k], stride 512
    float s00 = 0.f, s01 = 0.f, s10 = 0.f, s11 = 0.f;
    float s20 = 0.f, s21 = 0.f, s30 = 0.f, s31 = 0.f;
#pragma unroll
    for (int d4 = 0; d4 < 16; ++d4) {
      float k0v[4], k1v[4];
#pragma unroll
      for (int j = 0; j < 4; ++j) {
        k0v[j] = Kp[(size_t)(d4 * 4 + j) * 512];
        k1v[j] = Kp[(size_t)(d4 * 4 + j) * 512 + 256];
      }
      const float4 q0v = *(const float4*)&qs[0][d4 << 2];
      const float4 q1v = *(const float4*)&qs[1][d4 << 2];
      const float4 q2v = *(const float4*)&qs[2][d4 << 2];
      const float4 q3v = *(const float4*)&qs[3][d4 << 2];
      s00 = fmaf(q0v.x, k0v[0], s00); s00 = fmaf(q0v.y, k0v[1], s00);
      s00 = fmaf(q0v.z, k0v[2], s00); s00 = fmaf(q0v.w, k0v[3], s00);
      s01 = fmaf(q0v.x, k1v[0], s01); s01 = fmaf(q0v.y, k1v[1], s01);
      s01 = fmaf(q0v.z, k1v[2], s01); s01 = fmaf(q0v.w, k1v[3], s01);
      s10 = fmaf(q1v.x, k0v[0], s10); s10 = fmaf(q1v.y, k0v[1], s10);
      s10 = fmaf(q1v.z, k0v[2], s10); s10 = fmaf(q1v.w, k0v[3], s10);
      s11 = fmaf(q1v.x, k1v[0], s11); s11 = fmaf(q1v.y, k1v[1], s11);
      s11 = fmaf(q1v.z, k1v[2], s11); s11 = fmaf(q1v.w, k1v[3], s11);
      s20 = fmaf(q2v.x, k0v[0], s20); s20 = fmaf(q2v.y, k0v[1], s20);
      s20 = fmaf(q2v.z, k0v[2], s20); s20 = fmaf(q2v.w, k0v[3], s20);
      s21 = fmaf(q2v.x, k1v[0], s21); s21 = fmaf(q2v.y, k1v[1], s21);
      s21 = fmaf(q2v.z, k1v[2], s21); s21 = fmaf(q2v.w, k1v[3], s21);
      s30 = fmaf(q3v.x, k0v[0], s30); s30 = fmaf(q3v.y, k0v[1], s30);
      s30 = fmaf(q3v.z, k0v[2], s30); s30 = fmaf(q3v.w, k0v[3], s30);
      s31 = fmaf(q3v.x, k1v[0], s31); s31 = fmaf(q3v.y, k1v[1], s31);
      s31 = fmaf(q3v.z, k1v[2], s31); s31 = fmaf(q3v.w, k1v[3], s31);
    }
    // own-thread slots; re-read below by the same thread -> no barrier
    tfs[0][tid] = s00 * 0.125f; tfs[0][tid + 256] = s01 * 0.125f;
    tfs[1][tid] = s10 * 0.125f; tfs[1][tid + 256] = s11 * 0.125f;
    tfs[2][tid] = s20 * 0.125f; tfs[2][tid + 256] = s21 * 0.125f;
    tfs[3][tid] = s30 * 0.125f; tfs[3][tid + 256] = s31 * 0.125f;
  }

  // ---- phase A: row maxes (batched; one barrier for 4 rows) ----
  float scA[4], scB[4];
#pragma unroll
  for (int rr = 0; rr < 4; ++rr) {
    scA[rr] = tfs[rr][tid];
    scB[rr] = tfs[rr][tid + 256];
    float mx = fmaxf(scA[rr], scB[rr]);
    for (int m = 1; m < 64; m <<= 1) mx = fmaxf(mx, __shfl_xor(mx, m));
    if ((tid & 63) == 0) redA[rr][tid >> 6] = mx;
  }
  __syncthreads();

  // ---- phase B: exp + row sums (batched) ----
  float e0v[4], e1v[4];
#pragma unroll
  for (int rr = 0; rr < 4; ++rr) {
    const float rowmax = fmaxf(fmaxf(redA[rr][0], redA[rr][1]),
                               fmaxf(redA[rr][2], redA[rr][3]));
    e0v[rr] = expf(scA[rr] - rowmax);
    e1v[rr] = expf(scB[rr] - rowmax);
    float ssum = e0v[rr] + e1v[rr];
    for (int m = 1; m < 64; m <<= 1) ssum += __shfl_xor(ssum, m);
    if ((tid & 63) == 0) redB[rr][tid >> 6] = ssum;
  }
  __syncthreads();

  // ---- phase C: tf, thresholds, Qrow partials (batched) ----
#pragma unroll
  for (int rr = 0; rr < 4; ++rr) {
    const float tot = redB[rr][0] + redB[rr][1] + redB[rr][2] + redB[rr][3];
    const float t0 = e0v[rr] / tot, t1 = e1v[rr] / tot;
    tfs[rr][tid] = t0; tfs[rr][tid + 256] = t1;
    const float p0 = fmaf(0.5f, t0, 0.0009765625f);
    const float p1 = fmaf(0.5f, t1, 0.0009765625f);
    // swizzle: k -> ((k&31)>>2)*64 + (k>>5)*4 + (k&3)   (R13 verbatim)
    {
      const int k = tid;
      pscu[rr][(((k & 31) >> 2) << 6) + ((k >> 5) << 2) + (k & 3)] =
          ((uint32_t)ceilf(p0 * 8388608.0f)) << 9;
    }
    {
      const int k = tid + 256;
      pscu[rr][(((k & 31) >> 2) << 6) + ((k >> 5) << 2) + (k & 3)] =
          ((uint32_t)ceilf(p1 * 8388608.0f)) << 9;
    }
    float ql = (1.f - p0) * (1.f - p1);       // Qrow partial
    for (int m = 1; m < 64; m <<= 1) ql *= __shfl_xor(ql, m);
    if ((tid & 63) == 0) redQ[rr][tid >> 6] = ql;
  }
  __syncthreads();

  // ---- RNG: rolled rr loop; bit-identical draws to R13 ----
  const int n = tid >> 4, t = tid & 15;
  const int k0i = t << 5;
  for (int rr = 0; rr < 4; ++rr) {
    const float Qrow = redQ[rr][0] * redQ[rr][1] * redQ[rr][2] * redQ[rr][3];
    const uint32_t cbase = (uint32_t)(rbase + rr) * 8192u +
                           (uint32_t)n * 512u + (uint32_t)k0i + 42u;
    const uint32_t* psc = pscu[rr];
    const float* tf = tfs[rr];
    uint32_t bits = 0u;
#pragma unroll
    for (int jb = 0; jb < 32; jb += 8) {
      uint32_t x0[8], x1[8];
#pragma unroll
      for (int i = 0; i < 8; ++i) {
        const uint32_t c = cbase + (uint32_t)(jb + i);
        x0[i] = c;                        // round-1 fold: x0 was 0
        x1[i] = ROTL(c, 13) ^ c;
      }
      QR8(15) QR8(26) QR8(6)
      INJ8(42u, 0x1BD11BF1u)
      QR8(17) QR8(29) QR8(16) QR8(24)
      INJ8(0x1BD11BF0u, 2u)
      QR8(13) QR8(15) QR8(26) QR8(6)
      INJ8Y(45u)
      QR8(17) QR8(29) QR8(16) QR8(24)
      INJ8(42u, 0x1BD11BF4u)
      QR8(13) QR8(15) QR8(26) QR8(6)
      INJ8(0x1BD11BF0u, 5u)
      const uint4 pA = *(const uint4*)&psc[((jb >> 2) << 6) + (t << 2)];
      const uint4 pB = *(const uint4*)&psc[(((jb >> 2) + 1) << 6) + (t << 2)];
      bits |= (uint32_t)((x0[0] ^ x1[0]) < pA.x) << (jb + 0);
      bits |= (uint32_t)((x0[1] ^ x1[1]) < pA.y) << (jb + 1);
      bits |= (uint32_t)((x0[2] ^ x1[2]) < pA.z) << (jb + 2);
      bits |= (uint32_t)((x0[3] ^ x1[3]) < pA.w) << (jb + 3);
      bits |= (uint32_t)((x0[4] ^ x1[4]) < pB.x) << (jb + 4);
      bits |= (uint32_t)((x0[5] ^ x1[5]) < pB.y) << (jb + 5);
      bits |= (uint32_t)((x0[6] ^ x1[6]) < pB.z) << (jb + 6);
      bits |= (uint32_t)((x0[7] ^ x1[7]) < pB.w) << (jb + 7);
    }
    bitsS[rr][tid] = bits;

    // rare path: selected-term products
    float ptl = 1.f, ratl = 1.f;
    int cl = __popc(bits);
    {
      uint32_t bb = bits;
      while (bb) {
        const int j = __builtin_ctz(bb);
        bb &= bb - 1u;
        const float tv = tf[k0i + j];
        const float p = fmaf(0.5f, tv, 0.0009765625f);
        ptl *= tv;
        ratl *= p / (1.f - p);
      }
    }
#pragma unroll
    for (int m = 1; m < 16; m <<= 1) {
      ptl *= __shfl_xor(ptl, m);
      ratl *= __shfl_xor(ratl, m);
      cl += __shfl_xor(cl, m);
    }
    if (t == 0) {
      const float pp = Qrow * ratl;
      wr[rr][n] = (cl > 0 && pp > 0.f) ? (ptl / fmaxf(pp, 1e-38f)) : 0.f;
    }
  }
  __syncthreads();

  // ---- zero wa (aliases pscu; RNG reads done) ----
  float* waf = (float*)pscu;                    // [4*512]
  {
    const float4 z4 = make_float4(0.f, 0.f, 0.f, 0.f);
    ((float4*)waf)[tid] = z4;
    ((float4*)waf)[tid + 256] = z4;
  }
  __syncthreads();

  // ---- weight normalize + wa atomics (per row, no barrier needed between) --
  for (int rr = 0; rr < 4; ++rr) {
    float wsum = 0.f;
#pragma unroll
    for (int m2 = 0; m2 < 16; ++m2) wsum += wr[rr][m2];
    const float wn = (wsum > 0.f) ? (wr[rr][n] / fmaxf(wsum, 1e-38f)) : 0.0625f;
    float* war = waf + (rr << 9);
    uint32_t bb = bitsS[rr][tid];
    while (bb) {
      const int j = __builtin_ctz(bb);
      bb &= bb - 1u;
      atomicAdd(&war[k0i + j], wn);
    }
  }
  __syncthreads();

  // ---- row weight sums (batched) ----
#pragma unroll
  for (int rr = 0; rr < 4; ++rr) {
    float sp = waf[(rr << 9) + tid] + waf[(rr << 9) + tid + 256];
    for (int m = 1; m < 64; m <<= 1) sp += __shfl_xor(sp, m);
    if ((tid & 63) == 0) redS[rr][tid >> 6] = sp;
  }
  __syncthreads();

  // ---- per-wave sparse attn @ V: wave w owns row w; lane l owns d=l ----
  {
    const float was = redS[w][0] + redS[w][1] + redS[w][2] + redS[w][3];
    const float* Vb = V + ((size_t)(b * 8 + h) * 512) * 64;
    const float* war = waf + (w << 9);
    float o = 0.f;
    if (was > 0.f) {
      const float inv = 1.f / fmaxf(was, 1e-38f);
#pragma unroll 1
      for (int c = 0; c < 8; ++c) {
        const float v = war[(c << 6) + l];
        unsigned long long mask = __ballot(v > 0.f);
        while (mask) {
          const int j = __builtin_ctzll(mask);
          mask &= mask - 1ull;
          const int k = (c << 6) + j;
          o = fmaf(war[k] * inv, Vb[(size_t)k * 64 + l], o);
        }
      }
    } else {
      for (int k = 0; k < 512; ++k) o += Vb[(size_t)k * 64 + l];
      o *= 0.001953125f;
    }
    o_sT[l][w] = o;
  }
  __syncthreads();

  // ---- out-projection: Wo loads shared across the 4 rows ----
  {
    const float* Wh = Wo + ((size_t)h * 64) * 512;
    float a00 = 0.f, a01 = 0.f, a10 = 0.f, a11 = 0.f;
    float a20 = 0.f, a21 = 0.f, a30 = 0.f, a31 = 0.f;
#pragma unroll 8
    for (int dd = 0; dd < 64; ++dd) {
      const float4 o4 = *(const float4*)&o_sT[dd][0];   // broadcast b128
      const float w0 = Wh[(size_t)dd * 512 + tid];
      const float w1 = Wh[(size_t)dd * 512 + tid + 256];
      a00 = fmaf(o4.x, w0, a00); a01 = fmaf(o4.x, w1, a01);
      a10 = fmaf(o4.y, w0, a10); a11 = fmaf(o4.y, w1, a11);
      a20 = fmaf(o4.z, w0, a20); a21 = fmaf(o4.z, w1, a21);
      a30 = fmaf(o4.w, w0, a30); a31 = fmaf(o4.w, w1, a31);
    }
    float* orow = outp + ((size_t)(b * 512 + q0)) * 512;
    atomicAdd(&orow[tid], a00);         atomicAdd(&orow[tid + 256], a01);
    atomicAdd(&orow[512 + tid], a10);   atomicAdd(&orow[512 + tid + 256], a11);
    atomicAdd(&orow[1024 + tid], a20);  atomicAdd(&orow[1024 + tid + 256], a21);
    atomicAdd(&orow[1536 + tid], a30);  atomicAdd(&orow[1536 + tid + 256], a31);
  }
}

// ---------------------------------------------------------------------------
extern "C" void kernel_launch(void* const* d_in, const int* in_sizes, int n_in,
                              void* d_out, int out_size, void* d_ws,
                              size_t ws_size, hipStream_t stream) {
  const float* x  = (const float*)d_in[0];
  const float* Wq = (const float*)d_in[1];
  const float* bq = (const float*)d_in[2];
  const float* Wk = (const float*)d_in[3];
  const float* bk = (const float*)d_in[4];
  const float* Wv = (const float*)d_in[5];
  const float* bv = (const float*)d_in[6];
  const float* Wo = (const float*)d_in[7];
  const float* bo = (const float*)d_in[8];
  float* out = (float*)d_out;

  float* ws = (float*)d_ws;
  float* Qw = ws;                  // 524288 f32  [B,H,S,dk]
  float* KT = ws + 524288;         // 524288     [B,H,dk,S]
  float* Vw = ws + 1048576;        // 524288     [B,H,S,dk]

  dim3 gq(32, 8, 4);
  qkv_gemm<<<gq, 256, 0, stream>>>(x, Wq, bq, Wk, bk, Wv, bv, bo, out,
                                   Qw, KT, Vw);
  fused_sample<<<2048, 256, 0, stream>>>(Qw, KT, Vw, Wo, out);
}